// Round 5
// baseline (753.723 us; speedup 1.0000x reference)
//
#include <hip/hip_runtime.h>
#include <hip/hip_cooperative_groups.h>

namespace cg = cooperative_groups;

#define N_NODES 50000
#define N_EDGES 800000
#define D 128
#define NBKT 98       // ceil(50000/512) buckets of 512 dst nodes
#define BKT_SHIFT 9
#define BKT_CAP 16384 // padded per-bucket capacity
#define BIN_BLOCKS 196
#define EPB2 4096     // edges per binning job
#define NTILES 3125   // 50000 / 16 exactly
#define NJOBS (BIN_BLOCKS + 6330)

typedef __attribute__((ext_vector_type(8))) short bf16x8;
typedef __attribute__((ext_vector_type(4))) float f32x4;

__device__ __forceinline__ float bf2f(unsigned short u) {
  unsigned int v = ((unsigned int)u) << 16;
  return __uint_as_float(v);
}
__device__ __forceinline__ unsigned short f2bf(float f) {
  unsigned int u = __float_as_uint(f);
  unsigned int r = (u + 0x7fffu + ((u >> 16) & 1u)) >> 16;
  return (unsigned short)r;
}
__device__ __forceinline__ int edge_at(const int* ei, int idx, int is64) {
  return is64 ? ei[2 * idx] : ei[idx];
}

struct SharedMem {
  union {
    struct { int red[256]; int h[128]; int resv[128]; } prep;  // 2 KB
    struct { int h[512]; int ps[256]; int sc[512]; } p2;       // 5 KB
    struct { float sred[2][128]; } gr;                         // 1 KB
    float res[16 * 128];                                       // 8 KB
  } u;
  float nsc[128], nbt[128];
};

struct MegaArgs {
  const float *x, *Wl1, *bl1, *Wr1, *Wl2, *bl2, *Wr2;
  const float *g1w, *g1b, *g1a, *g2w, *g2b, *g2a, *Wres, *bres;
  const int* ei;
  unsigned short *xb, *buf0, *agg, *pre2, *wb, *srcs;
  unsigned int* binned;
  int *cursor, *off;
  float* stats;
  float* outp;
};

// ---- phase 0: casts + edge binning (jobs grid-strided) ------------------
__device__ __forceinline__ void ph_prep(const MegaArgs& a, SharedMem* sm, int grid) {
  int t = threadIdx.x;
  for (int job = blockIdx.x; job < NJOBS; job += grid) {
    if (job >= BIN_BLOCKS) {
      int bc = job - BIN_BLOCKS;
      const float* src;
      unsigned short* dst;
      int i;
      if (bc < 6250) {
        src = a.x; dst = a.xb; i = bc * 256 + t;
      } else {
        int b2 = bc - 6250;
        int m = b2 >> 4;
        i = (b2 & 15) * 256 + t;
        src = (m == 0) ? a.Wl1 : (m == 1) ? a.Wr1 : (m == 2) ? a.Wl2 : (m == 3) ? a.Wr2 : a.Wres;
        dst = a.wb + m * 16384;
      }
      float4 v = ((const float4*)src)[i];
      ushort4 o;
      o.x = f2bf(v.x); o.y = f2bf(v.y); o.z = f2bf(v.z); o.w = f2bf(v.w);
      ((ushort4*)dst)[i] = o;
    } else {
      int* red = sm->u.prep.red;
      int* h = sm->u.prep.h;
      int* resv = sm->u.prep.resv;
      int start = job * EPB2;
      int end = min(start + EPB2, N_EDGES);
      int acc = 0;
      for (int k = start + t; k < end; k += 256) acc |= a.ei[2 * k + 1];
      red[t] = acc;
      if (t < 128) h[t] = 0;
      __syncthreads();
      for (int s2 = 128; s2 > 0; s2 >>= 1) {
        if (t < s2) red[t] |= red[t + s2];
        __syncthreads();
      }
      int is64 = (red[0] == 0) ? 1 : 0;
      for (int e = start + t; e < end; e += 256) {
        int d = edge_at(a.ei, N_EDGES + e, is64);
        if ((unsigned)d < N_NODES) atomicAdd(&h[d >> BKT_SHIFT], 1);
      }
      __syncthreads();
      if (t < NBKT) {
        resv[t] = h[t] ? (t * BKT_CAP + atomicAdd(&a.cursor[t], h[t])) : 0;
        h[t] = 0;
      }
      __syncthreads();
      for (int e = start + t; e < end; e += 256) {
        int d = edge_at(a.ei, N_EDGES + e, is64);
        int sv = edge_at(a.ei, e, is64);
        if ((unsigned)d < N_NODES && (unsigned)sv < N_NODES) {
          int bkt = d >> BKT_SHIFT;
          int r = atomicAdd(&h[bkt], 1);
          int pos = resv[bkt] + r;
          if (pos < (bkt + 1) * BKT_CAP) a.binned[pos] = (unsigned)sv | ((unsigned)d << 16);
        }
      }
      __syncthreads();
    }
  }
}

// ---- phase 1: per-bucket CSR (256-thread proven form, bucket-strided) ---
__device__ __forceinline__ void ph_pass2(const int* cursor, const unsigned int* binned,
                                         int* off, unsigned short* srcs,
                                         SharedMem* sm, int grid) {
  int t = threadIdx.x;
  int* h = sm->u.p2.h;
  int* ps = sm->u.p2.ps;
  int* sc = sm->u.p2.sc;
  for (int b = blockIdx.x; b < NBKT; b += grid) {
    int base = b * BKT_CAP;
    int cnt = min(cursor[b], BKT_CAP);
    h[t] = 0; h[t + 256] = 0;
    __syncthreads();
    for (int e = base + t; e < base + cnt; e += 256) {
      unsigned v = binned[e];
      atomicAdd(&h[(int)(v >> 16) - (b << BKT_SHIFT)], 1);
    }
    __syncthreads();
    int pair = h[2 * t] + h[2 * t + 1];
    ps[t] = pair;
    __syncthreads();
    for (int s = 1; s < 256; s <<= 1) {
      int add = (t >= s) ? ps[t - s] : 0;
      __syncthreads();
      ps[t] += add;
      __syncthreads();
    }
    int pexcl = ps[t] - pair;
    sc[2 * t] = pexcl;
    sc[2 * t + 1] = pexcl + h[2 * t];
    __syncthreads();
    h[t] = 0; h[t + 256] = 0;
    off[b * 513 + t] = base + sc[t];
    off[b * 513 + t + 256] = base + sc[t + 256];
    if (t == 0) off[b * 513 + 512] = base + cnt;
    __syncthreads();
    for (int e = base + t; e < base + cnt; e += 256) {
      unsigned v = binned[e];
      int l = (int)(v >> 16) - (b << BKT_SHIFT);
      int r = atomicAdd(&h[l], 1);
      srcs[base + sc[l] + r] = (unsigned short)(v & 0xffffu);
    }
    __syncthreads();
  }
}

// ---- phases 2/4: mean aggregation (R0-proven body, node-strided) --------
template <bool NORM>
__device__ __forceinline__ void accum8(float* a, uint4 v, const float* sc,
                                       const float* bt) {
  const unsigned int* pv = (const unsigned int*)&v;
#pragma unroll
  for (int h = 0; h < 4; ++h) {
    float lo = bf2f((unsigned short)(pv[h] & 0xffffu));
    float hi = bf2f((unsigned short)(pv[h] >> 16));
    if (NORM) {
      a[2 * h] += fmaxf(fmaf(sc[2 * h], lo, bt[2 * h]), 0.f);
      a[2 * h + 1] += fmaxf(fmaf(sc[2 * h + 1], hi, bt[2 * h + 1]), 0.f);
    } else {
      a[2 * h] += lo;
      a[2 * h + 1] += hi;
    }
  }
}

template <bool NORM>
__device__ __forceinline__ void ph_agg(const unsigned short* feat, const int* off,
                                       const unsigned short* srcs, const float* Sin,
                                       const float* gw, const float* gb,
                                       const float* ga, unsigned short* agg, int grid) {
  int wv = threadIdx.x >> 6;
  int lane = threadIdx.x & 63;
  int q = lane >> 4, s = lane & 15;

  float sc[8], bt[8];
  if (NORM) {
    const float invN = 1.0f / (float)N_NODES;
#pragma unroll
    for (int i = 0; i < 8; ++i) {
      int f = s * 8 + i;
      float m = Sin[f] * invN;
      float ex2 = Sin[128 + f] * invN;
      float af = ga[f];
      float var = fmaxf(ex2 - (2.f * af - af * af) * m * m, 0.f);
      float rstd = rsqrtf(var + 1e-5f);
      sc[i] = gw[f] * rstd;
      bt[i] = gb[f] - sc[i] * af * m;
    }
  }

  const uint4* fp = (const uint4*)feat;
  for (int node = blockIdx.x * 4 + wv; node < N_NODES; node += grid * 4) {
    int oidx = (node >> BKT_SHIFT) * 513 + (node & 511);
    int b = off[oidx], e = off[oidx + 1];
    float a[8] = {0.f, 0.f, 0.f, 0.f, 0.f, 0.f, 0.f, 0.f};
    for (int cb = b; cb < e; cb += 64) {
      int n = min(64, e - cb);
      int jv = (lane < n) ? (int)srcs[cb + lane] : 0;
      int kmax = (n + 3) >> 2;
      int k = 0;
      for (; k + 2 <= kmax; k += 2) {
        int t0 = 4 * k + q;
        int t1 = t0 + 4;
        int j0 = __shfl(jv, t0);
        int j1 = __shfl(jv, t1);
        uint4 v0 = fp[j0 * 16 + s];
        uint4 v1 = fp[j1 * 16 + s];
        if (t0 < n) accum8<NORM>(a, v0, sc, bt);
        if (t1 < n) accum8<NORM>(a, v1, sc, bt);
      }
      if (k < kmax) {
        int t0 = 4 * k + q;
        int j0 = __shfl(jv, t0);
        uint4 v0 = fp[j0 * 16 + s];
        if (t0 < n) accum8<NORM>(a, v0, sc, bt);
      }
    }
#pragma unroll
    for (int i = 0; i < 8; ++i) {
      a[i] += __shfl_xor(a[i], 16);
      a[i] += __shfl_xor(a[i], 32);
    }
    if (q == 0) {
      float inv = 1.0f / (float)max(e - b, 1);
      uint4 o;
      o.x = (unsigned)f2bf(a[0] * inv) | ((unsigned)f2bf(a[1] * inv) << 16);
      o.y = (unsigned)f2bf(a[2] * inv) | ((unsigned)f2bf(a[3] * inv) << 16);
      o.z = (unsigned)f2bf(a[4] * inv) | ((unsigned)f2bf(a[5] * inv) << 16);
      o.w = (unsigned)f2bf(a[6] * inv) | ((unsigned)f2bf(a[7] * inv) << 16);
      ((uint4*)agg)[node * 16 + s] = o;
    }
  }
}

// ---- phases 3/5: dual GEMM + bias + stats (single-tile, tile-strided) ---
template <bool NORMB>
__device__ __forceinline__ void ph_gemm(const unsigned short* A, const unsigned short* B,
                                        const unsigned short* W1, const unsigned short* W2,
                                        const float* bias, unsigned short* outv,
                                        float* S, const float* Sin, const float* gw,
                                        const float* gb, const float* ga,
                                        SharedMem* sm, int grid) {
  const int tid = threadIdx.x;
  const int lane = tid & 63;
  const int wv = tid >> 6;
  const int quad = lane >> 4;
  const int l16 = lane & 15;
  const int colBase = wv * 32;

  if (NORMB) {
    if (tid < 128) {
      const float invN = 1.0f / (float)N_NODES;
      float m = Sin[tid] * invN;
      float ex2 = Sin[128 + tid] * invN;
      float af = ga[tid];
      float var = fmaxf(ex2 - (2.f * af - af * af) * m * m, 0.f);
      float rstd = rsqrtf(var + 1e-5f);
      float scv = gw[tid] * rstd;
      sm->nsc[tid] = scv;
      sm->nbt[tid] = gb[tid] - scv * af * m;
    }
    __syncthreads();
  }

  float bv[2] = {bias[colBase + l16], bias[colBase + 16 + l16]};
  float p1[2] = {0.f, 0.f}, p2[2] = {0.f, 0.f};

  for (int t0 = blockIdx.x; t0 < NTILES; t0 += grid) {
    int arow = t0 * 16 + l16;
    bf16x8 af[4], bfr[4];
#pragma unroll
    for (int ks = 0; ks < 4; ++ks) {
      af[ks] = *((const bf16x8*)&A[arow * 128 + ks * 32 + quad * 8]);
      bfr[ks] = *((const bf16x8*)&B[arow * 128 + ks * 32 + quad * 8]);
    }
    if (NORMB) {
#pragma unroll
      for (int ks = 0; ks < 4; ++ks) {
        int f0 = ks * 32 + quad * 8;
#pragma unroll
        for (int j = 0; j < 8; ++j) {
          float xv = bf2f((unsigned short)bfr[ks][j]);
          bfr[ks][j] = (short)f2bf(fmaxf(fmaf(sm->nsc[f0 + j], xv, sm->nbt[f0 + j]), 0.f));
        }
      }
    }
#pragma unroll
    for (int c2 = 0; c2 < 2; ++c2) {
      int col = colBase + c2 * 16 + l16;
      f32x4 acc = (f32x4){0.f, 0.f, 0.f, 0.f};
#pragma unroll
      for (int ks = 0; ks < 4; ++ks) {
        bf16x8 w1 = *((const bf16x8*)&W1[col * 128 + ks * 32 + quad * 8]);
        bf16x8 w2 = *((const bf16x8*)&W2[col * 128 + ks * 32 + quad * 8]);
        acc = __builtin_amdgcn_mfma_f32_16x16x32_bf16(af[ks], w1, acc, 0, 0, 0);
        acc = __builtin_amdgcn_mfma_f32_16x16x32_bf16(bfr[ks], w2, acc, 0, 0, 0);
      }
#pragma unroll
      for (int g = 0; g < 4; ++g) {
        int row = t0 * 16 + quad * 4 + g;
        float v = acc[g] + bv[c2];
        outv[row * 128 + col] = f2bf(v);
        p1[c2] += v;
        p2[c2] += v * v;
      }
    }
  }

#pragma unroll
  for (int c2 = 0; c2 < 2; ++c2) {
    p1[c2] += __shfl_xor(p1[c2], 16); p1[c2] += __shfl_xor(p1[c2], 32);
    p2[c2] += __shfl_xor(p2[c2], 16); p2[c2] += __shfl_xor(p2[c2], 32);
  }
  __syncthreads();  // union area free before sred writes
  if (quad == 0) {
#pragma unroll
    for (int c2 = 0; c2 < 2; ++c2) {
      sm->u.gr.sred[0][colBase + c2 * 16 + l16] = p1[c2];
      sm->u.gr.sred[1][colBase + c2 * 16 + l16] = p2[c2];
    }
  }
  __syncthreads();
  if (tid < 128) atomicAdd(&S[tid], sm->u.gr.sred[0][tid]);
  else atomicAdd(&S[tid], sm->u.gr.sred[1][tid - 128]);
  __syncthreads();
}

// ---- phase 6: residual GEMM (fp32) + GraphNorm + ReLU -> d_out ----------
__device__ __forceinline__ void ph_final(const unsigned short* pre, const unsigned short* xb,
                                         const unsigned short* Wres, const float* bres,
                                         const float* S, const float* gw, const float* gb,
                                         const float* ga, float* outp,
                                         SharedMem* sm, int grid) {
  const int tid = threadIdx.x;
  const int lane = tid & 63;
  const int wv = tid >> 6;
  const int quad = lane >> 4;
  const int l16 = lane & 15;
  const int colBase = wv * 32;

  if (tid < 128) {
    const float invN = 1.0f / (float)N_NODES;
    float m = S[tid] * invN;
    float ex2 = S[128 + tid] * invN;
    float af = ga[tid];
    float var = fmaxf(ex2 - (2.f * af - af * af) * m * m, 0.f);
    float rstd = rsqrtf(var + 1e-5f);
    float scv = gw[tid] * rstd;
    sm->nsc[tid] = scv;
    sm->nbt[tid] = gb[tid] - scv * af * m;
  }
  __syncthreads();

  float bvR[2] = {bres[colBase + l16], bres[colBase + 16 + l16]};
  bf16x8 wrf[2][4];
#pragma unroll
  for (int c2 = 0; c2 < 2; ++c2)
#pragma unroll
    for (int ks = 0; ks < 4; ++ks)
      wrf[c2][ks] = *((const bf16x8*)&Wres[(colBase + c2 * 16 + l16) * 128 + ks * 32 + quad * 8]);

  const int row16 = tid >> 4, cg16 = tid & 15;
  for (int t0 = blockIdx.x; t0 < NTILES; t0 += grid) {
    int arow = t0 * 16 + l16;
    bf16x8 af[4];
#pragma unroll
    for (int ks = 0; ks < 4; ++ks)
      af[ks] = *((const bf16x8*)&xb[arow * 128 + ks * 32 + quad * 8]);
#pragma unroll
    for (int c2 = 0; c2 < 2; ++c2) {
      f32x4 acc = (f32x4){0.f, 0.f, 0.f, 0.f};
#pragma unroll
      for (int ks = 0; ks < 4; ++ks)
        acc = __builtin_amdgcn_mfma_f32_16x16x32_bf16(af[ks], wrf[c2][ks], acc, 0, 0, 0);
#pragma unroll
      for (int g = 0; g < 4; ++g)
        sm->u.res[(quad * 4 + g) * 128 + colBase + c2 * 16 + l16] = acc[g] + bvR[c2];
    }
    __syncthreads();
    {
      uint4 v = ((const uint4*)pre)[(t0 * 16 + row16) * 16 + cg16];
      const unsigned* pv = (const unsigned*)&v;
      const float4* rr = (const float4*)&sm->u.res[row16 * 128 + cg16 * 8];
      float4 r0 = rr[0], r1 = rr[1];
      float o[8];
#pragma unroll
      for (int hh = 0; hh < 4; ++hh) {
        float lo = bf2f((unsigned short)(pv[hh] & 0xffffu));
        float hi = bf2f((unsigned short)(pv[hh] >> 16));
        int f0 = cg16 * 8 + 2 * hh;
        o[2 * hh] = fmaxf(fmaf(sm->nsc[f0], lo, sm->nbt[f0]), 0.f);
        o[2 * hh + 1] = fmaxf(fmaf(sm->nsc[f0 + 1], hi, sm->nbt[f0 + 1]), 0.f);
      }
      o[0] += r0.x; o[1] += r0.y; o[2] += r0.z; o[3] += r0.w;
      o[4] += r1.x; o[5] += r1.y; o[6] += r1.z; o[7] += r1.w;
      float4* op = (float4*)&outp[(t0 * 16 + row16) * 128 + cg16 * 8];
      op[0] = make_float4(o[0], o[1], o[2], o[3]);
      op[1] = make_float4(o[4], o[5], o[6], o[7]);
    }
    __syncthreads();
  }
}

// ---- the cooperative mega-kernel ----------------------------------------
__global__ __launch_bounds__(256, 4) void k_mega(MegaArgs a) {
  __shared__ SharedMem sm;
  cg::grid_group g = cg::this_grid();
  int grid = gridDim.x;
  ph_prep(a, &sm, grid);
  g.sync();
  ph_pass2(a.cursor, a.binned, a.off, a.srcs, &sm, grid);
  g.sync();
  ph_agg<false>(a.xb, a.off, a.srcs, nullptr, nullptr, nullptr, nullptr, a.agg, grid);
  g.sync();
  ph_gemm<false>(a.agg, a.xb, a.wb, a.wb + 16384, a.bl1, a.buf0, a.stats,
                 nullptr, nullptr, nullptr, nullptr, &sm, grid);
  g.sync();
  ph_agg<true>(a.buf0, a.off, a.srcs, a.stats, a.g1w, a.g1b, a.g1a, a.agg, grid);
  g.sync();
  ph_gemm<true>(a.agg, a.buf0, a.wb + 32768, a.wb + 49152, a.bl2, a.pre2,
                a.stats + 256, a.stats, a.g1w, a.g1b, a.g1a, &sm, grid);
  g.sync();
  ph_final(a.pre2, a.xb, a.wb + 65536, a.bres, a.stats + 256, a.g2w, a.g2b, a.g2a,
           a.outp, &sm, grid);
}

// ---- fallback wrappers (classic multi-launch path) ----------------------
__global__ __launch_bounds__(256) void g_prep(MegaArgs a) {
  __shared__ SharedMem sm;
  ph_prep(a, &sm, gridDim.x);
}
__global__ __launch_bounds__(256) void g_pass2(MegaArgs a) {
  __shared__ SharedMem sm;
  ph_pass2(a.cursor, a.binned, a.off, a.srcs, &sm, gridDim.x);
}
template <bool NORM>
__global__ __launch_bounds__(256) void g_agg(MegaArgs a) {
  if (NORM)
    ph_agg<true>(a.buf0, a.off, a.srcs, a.stats, a.g1w, a.g1b, a.g1a, a.agg, gridDim.x);
  else
    ph_agg<false>(a.xb, a.off, a.srcs, nullptr, nullptr, nullptr, nullptr, a.agg, gridDim.x);
}
template <bool NORMB>
__global__ __launch_bounds__(256) void g_gemm(MegaArgs a) {
  __shared__ SharedMem sm;
  if (NORMB)
    ph_gemm<true>(a.agg, a.buf0, a.wb + 32768, a.wb + 49152, a.bl2, a.pre2,
                  a.stats + 256, a.stats, a.g1w, a.g1b, a.g1a, &sm, gridDim.x);
  else
    ph_gemm<false>(a.agg, a.xb, a.wb, a.wb + 16384, a.bl1, a.buf0, a.stats,
                   nullptr, nullptr, nullptr, nullptr, &sm, gridDim.x);
}
__global__ __launch_bounds__(256) void g_final(MegaArgs a) {
  __shared__ SharedMem sm;
  ph_final(a.pre2, a.xb, a.wb + 65536, a.bres, a.stats + 256, a.g2w, a.g2b, a.g2a,
           a.outp, &sm, gridDim.x);
}

extern "C" void kernel_launch(void* const* d_in, const int* in_sizes, int n_in,
                              void* d_out, int out_size, void* d_ws, size_t ws_size,
                              hipStream_t stream) {
  char* w = (char*)d_ws;
  const size_t FEATB = (size_t)N_NODES * D * 2;  // 12.8 MB bf16 buffer
  char* ip = w + 4 * FEATB;
  const size_t NEED = 4 * FEATB + 3578776;
  if (ws_size < NEED) {
    hipMemsetAsync(d_out, 0, (size_t)out_size * 4, stream);
    return;
  }

  MegaArgs a;
  a.x = (const float*)d_in[0];
  a.ei = (const int*)d_in[1];
  a.Wl1 = (const float*)d_in[2];
  a.bl1 = (const float*)d_in[3];
  a.Wr1 = (const float*)d_in[4];
  a.Wl2 = (const float*)d_in[5];
  a.bl2 = (const float*)d_in[6];
  a.Wr2 = (const float*)d_in[7];
  a.g1w = (const float*)d_in[8];
  a.g1b = (const float*)d_in[9];
  a.g1a = (const float*)d_in[10];
  a.g2w = (const float*)d_in[11];
  a.g2b = (const float*)d_in[12];
  a.g2a = (const float*)d_in[13];
  a.Wres = (const float*)d_in[14];
  a.bres = (const float*)d_in[15];
  a.xb = (unsigned short*)(w);
  a.buf0 = (unsigned short*)(w + FEATB);
  a.agg = (unsigned short*)(w + 2 * FEATB);
  a.pre2 = (unsigned short*)(w + 3 * FEATB);  // former resb slot
  a.stats = (float*)ip;                        // 2048 B
  a.cursor = (int*)(ip + 2064);                // 512 B
  a.off = (int*)(ip + 2576);                   // 201096 B
  a.srcs = (unsigned short*)(ip + 203672);     // 3211264 B
  a.wb = (unsigned short*)(ip + 3414936);      // 163840 B
  a.binned = (unsigned int*)a.agg;             // alias; pre-agg use only
  a.outp = (float*)d_out;

  // zero stats (512 f32) + cursor in one tiny memset
  hipMemsetAsync(ip, 0, 2576, stream);

  int nb = 0;
  hipError_t oe = hipOccupancyMaxActiveBlocksPerMultiprocessor(&nb, k_mega, 256, 0);
  int dev = 0, ncu = 256;
  hipGetDevice(&dev);
  hipDeviceGetAttribute(&ncu, hipDeviceAttributeMultiprocessorCount, dev);
  if (oe != hipSuccess || nb < 1) nb = 1;
  long grid = (long)nb * (long)ncu;
  if (grid > 4096) grid = 4096;
  if (grid < 256) grid = 256;

  void* args[] = {(void*)&a};
  hipError_t le = hipLaunchCooperativeKernel(k_mega, dim3((unsigned)grid), dim3(256),
                                             args, 0, stream);
  if (le != hipSuccess) {  // classic multi-launch fallback
    g_prep<<<NJOBS, 256, 0, stream>>>(a);
    g_pass2<<<NBKT, 256, 0, stream>>>(a);
    g_agg<false><<<12500, 256, 0, stream>>>(a);
    g_gemm<false><<<1024, 256, 0, stream>>>(a);
    g_agg<true><<<12500, 256, 0, stream>>>(a);
    g_gemm<true><<<1024, 256, 0, stream>>>(a);
    g_final<<<1024, 256, 0, stream>>>(a);
  }
}

// Round 6
// 354.867 us; speedup vs baseline: 2.1240x; 2.1240x over previous
//
#include <hip/hip_runtime.h>

#define N_NODES 50000
#define N_EDGES 800000
#define D 128
#define NBKT 98       // ceil(50000/512) buckets of 512 dst nodes
#define BKT_SHIFT 9
#define BKT_CAP 16384 // padded per-bucket capacity
#define BIN_BLOCKS 196
#define EPB2 4096     // edges per binning block (196 blocks)
#define NTILES 3125   // 50000 / 16 exactly
#define ATS 136       // atile row stride in shorts (272 B: 16B-aligned, bank-spread)

typedef __attribute__((ext_vector_type(8))) short bf16x8;
typedef __attribute__((ext_vector_type(4))) float f32x4;

__device__ __forceinline__ float bf2f(unsigned short u) {
  unsigned int v = ((unsigned int)u) << 16;
  return __uint_as_float(v);
}
__device__ __forceinline__ unsigned short f2bf(float f) {
  unsigned int u = __float_as_uint(f);
  unsigned int r = (u + 0x7fffu + ((u >> 16) & 1u)) >> 16;
  return (unsigned short)r;
}
__device__ __forceinline__ int edge_at(const int* ei, int idx, int is64) {
  return is64 ? ei[2 * idx] : ei[idx];
}

// ---- merged: edge binning (196 blocks, per-block dtype detect) + casts --
__global__ __launch_bounds__(256) void k_prep(const float* __restrict__ x,
                                              const float* __restrict__ w0,
                                              const float* __restrict__ w1,
                                              const float* __restrict__ w2,
                                              const float* __restrict__ w3,
                                              const float* __restrict__ w4,
                                              unsigned short* __restrict__ xb,
                                              unsigned short* __restrict__ wout,
                                              const int* __restrict__ ei,
                                              int* __restrict__ cursor,
                                              unsigned int* __restrict__ binned) {
  int b = blockIdx.x;
  if (b >= BIN_BLOCKS) {
    int bc = b - BIN_BLOCKS;
    const float* src;
    unsigned short* dst;
    int i;
    if (bc < 6250) {
      src = x; dst = xb; i = bc * 256 + threadIdx.x;
    } else {
      int b2 = bc - 6250;
      int m = b2 >> 4;
      i = (b2 & 15) * 256 + threadIdx.x;
      src = (m == 0) ? w0 : (m == 1) ? w1 : (m == 2) ? w2 : (m == 3) ? w3 : w4;
      dst = wout + m * 16384;
    }
    float4 v = ((const float4*)src)[i];
    ushort4 o;
    o.x = f2bf(v.x); o.y = f2bf(v.y); o.z = f2bf(v.z); o.w = f2bf(v.w);
    ((ushort4*)dst)[i] = o;
    return;
  }
  __shared__ int red[256];
  __shared__ int h[128];
  __shared__ int resv[128];
  int t = threadIdx.x;
  int start = b * EPB2;
  int end = min(start + EPB2, N_EDGES);
  int acc = 0;
  for (int k = start + t; k < end; k += 256) acc |= ei[2 * k + 1];
  red[t] = acc;
  if (t < 128) h[t] = 0;
  __syncthreads();
  for (int s2 = 128; s2 > 0; s2 >>= 1) {
    if (t < s2) red[t] |= red[t + s2];
    __syncthreads();
  }
  int is64 = (red[0] == 0) ? 1 : 0;
  for (int e = start + t; e < end; e += 256) {
    int d = edge_at(ei, N_EDGES + e, is64);
    if ((unsigned)d < N_NODES) atomicAdd(&h[d >> BKT_SHIFT], 1);
  }
  __syncthreads();
  if (t < NBKT) {
    resv[t] = h[t] ? (t * BKT_CAP + atomicAdd(&cursor[t], h[t])) : 0;
    h[t] = 0;
  }
  __syncthreads();
  for (int e = start + t; e < end; e += 256) {
    int d = edge_at(ei, N_EDGES + e, is64);
    int sv = edge_at(ei, e, is64);
    if ((unsigned)d < N_NODES && (unsigned)sv < N_NODES) {
      int bkt = d >> BKT_SHIFT;
      int r = atomicAdd(&h[bkt], 1);
      int pos = resv[bkt] + r;
      if (pos < (bkt + 1) * BKT_CAP) binned[pos] = (unsigned)sv | ((unsigned)d << 16);
    }
  }
}

// ---- per-bucket CSR: off (bucket-padded, stride 513) + srcs scatter -----
__global__ __launch_bounds__(512) void k_pass2(const int* __restrict__ cursor,
                                               const unsigned int* __restrict__ binned,
                                               int* __restrict__ off,
                                               unsigned short* __restrict__ srcs) {
  __shared__ int h[512];
  __shared__ int sc[512];
  __shared__ int sx[512];
  int t = threadIdx.x;
  int b = blockIdx.x;
  int base = b * BKT_CAP;
  int cnt = min(cursor[b], BKT_CAP);
  h[t] = 0;
  __syncthreads();
  for (int e = base + t; e < base + cnt; e += 512) {
    unsigned v = binned[e];
    atomicAdd(&h[(int)(v >> 16) - (b << BKT_SHIFT)], 1);
  }
  __syncthreads();
  int mine = h[t];
  sc[t] = mine;
  __syncthreads();
  for (int s = 1; s < 512; s <<= 1) {
    int add = (t >= s) ? sc[t - s] : 0;
    __syncthreads();
    sc[t] += add;
    __syncthreads();
  }
  int excl = sc[t] - mine;
  sx[t] = excl;
  off[b * 513 + t] = base + excl;
  if (t == 0) off[b * 513 + 512] = base + cnt;
  h[t] = 0;
  __syncthreads();
  for (int e = base + t; e < base + cnt; e += 512) {
    unsigned v = binned[e];
    int l = (int)(v >> 16) - (b << BKT_SHIFT);
    int r = atomicAdd(&h[l], 1);
    srcs[base + sx[l] + r] = (unsigned short)(v & 0xffffu);
  }
}

// ---- agg accumulate helper (R0-proven scalar form) ----------------------
template <bool NORM>
__device__ __forceinline__ void accum8(float* a, uint4 v, const float* sc,
                                       const float* bt) {
  const unsigned int* pv = (const unsigned int*)&v;
#pragma unroll
  for (int h = 0; h < 4; ++h) {
    float lo = bf2f((unsigned short)(pv[h] & 0xffffu));
    float hi = bf2f((unsigned short)(pv[h] >> 16));
    if (NORM) {
      a[2 * h] += fmaxf(fmaf(sc[2 * h], lo, bt[2 * h]), 0.f);
      a[2 * h + 1] += fmaxf(fmaf(sc[2 * h + 1], hi, bt[2 * h + 1]), 0.f);
    } else {
      a[2 * h] += lo;
      a[2 * h + 1] += hi;
    }
  }
}

// ---- fused per-tile [aggregate 16 rows -> LDS -> dual GEMM + stats] -----
// L2=false: layer1 (no norms, FUSERES residual GEMM on B).
// L2=true : layer2 (norm+relu on gathered features AND on B row; no residual).
template <bool L2>
__global__ __launch_bounds__(256) void k_fused(const unsigned short* __restrict__ feat,
                                               const int* __restrict__ off,
                                               const unsigned short* __restrict__ srcs,
                                               const unsigned short* __restrict__ W1,
                                               const unsigned short* __restrict__ W2,
                                               const unsigned short* __restrict__ Wres,
                                               const float* __restrict__ bias,
                                               const float* __restrict__ bres,
                                               unsigned short* __restrict__ outv,
                                               unsigned short* __restrict__ outres,
                                               float* __restrict__ S,
                                               const float* __restrict__ Sin,
                                               const float* __restrict__ gw,
                                               const float* __restrict__ gb,
                                               const float* __restrict__ ga) {
  __shared__ unsigned short atile[16 * ATS];  // 4352 B aggregated tile
  __shared__ float sred[2][128];
  __shared__ float nsc[128], nbt[128];
  const int tid = threadIdx.x;
  const int lane = tid & 63;
  const int wv = tid >> 6;
  const int q = lane >> 4;
  const int s = lane & 15;
  const int tile = blockIdx.x;

  if (L2) {
    if (tid < 128) {
      const float invN = 1.0f / (float)N_NODES;
      float m = Sin[tid] * invN;
      float ex2 = Sin[128 + tid] * invN;
      float af = ga[tid];
      float var = fmaxf(ex2 - (2.f * af - af * af) * m * m, 0.f);
      float rstd = rsqrtf(var + 1e-5f);
      float scv = gw[tid] * rstd;
      nsc[tid] = scv;
      nbt[tid] = gb[tid] - scv * af * m;
    }
    __syncthreads();
  }
  float sc[8], bt[8];
  if (L2) {
#pragma unroll
    for (int i = 0; i < 8; ++i) { sc[i] = nsc[s * 8 + i]; bt[i] = nbt[s * 8 + i]; }
  }

  const uint4* fp = (const uint4*)feat;

  // ---- aggregate the tile's 16 nodes: wave wv owns rows wv*4..wv*4+3 ----
  for (int it = 0; it < 4; ++it) {
    int node = tile * 16 + wv * 4 + it;
    int oidx = (node >> BKT_SHIFT) * 513 + (node & 511);
    int b = off[oidx], e = off[oidx + 1];
    float a[8] = {0.f, 0.f, 0.f, 0.f, 0.f, 0.f, 0.f, 0.f};
    for (int cb = b; cb < e; cb += 64) {
      int n = min(64, e - cb);
      int jv = (lane < n) ? (int)srcs[cb + lane] : 0;
      int kmax = (n + 3) >> 2;
      int k = 0;
      for (; k + 2 <= kmax; k += 2) {
        int t0 = 4 * k + q;
        int t1 = t0 + 4;
        int j0 = __shfl(jv, t0);
        int j1 = __shfl(jv, t1);
        uint4 v0 = fp[j0 * 16 + s];
        uint4 v1 = fp[j1 * 16 + s];
        if (t0 < n) accum8<L2>(a, v0, sc, bt);
        if (t1 < n) accum8<L2>(a, v1, sc, bt);
      }
      if (k < kmax) {
        int t0 = 4 * k + q;
        int j0 = __shfl(jv, t0);
        uint4 v0 = fp[j0 * 16 + s];
        if (t0 < n) accum8<L2>(a, v0, sc, bt);
      }
    }
#pragma unroll
    for (int i = 0; i < 8; ++i) {
      a[i] += __shfl_xor(a[i], 16);
      a[i] += __shfl_xor(a[i], 32);
    }
    if (q == 0) {
      float inv = 1.0f / (float)max(e - b, 1);
      uint4 o;
      o.x = (unsigned)f2bf(a[0] * inv) | ((unsigned)f2bf(a[1] * inv) << 16);
      o.y = (unsigned)f2bf(a[2] * inv) | ((unsigned)f2bf(a[3] * inv) << 16);
      o.z = (unsigned)f2bf(a[4] * inv) | ((unsigned)f2bf(a[5] * inv) << 16);
      o.w = (unsigned)f2bf(a[6] * inv) | ((unsigned)f2bf(a[7] * inv) << 16);
      *((uint4*)&atile[(wv * 4 + it) * ATS + s * 8]) = o;
    }
  }
  __syncthreads();

  // ---- dual GEMM on the tile (A from LDS, B row from global) ------------
  const int l16 = s;
  const int quad = q;
  const int colBase = wv * 32;
  const int arow = tile * 16 + l16;
  bf16x8 af[4], bfr[4];
#pragma unroll
  for (int ks = 0; ks < 4; ++ks) {
    af[ks] = *((const bf16x8*)&atile[l16 * ATS + ks * 32 + quad * 8]);
    bfr[ks] = *((const bf16x8*)&feat[arow * 128 + ks * 32 + quad * 8]);
  }
  if (L2) {
#pragma unroll
    for (int ks = 0; ks < 4; ++ks) {
      int f0 = ks * 32 + quad * 8;
#pragma unroll
      for (int j = 0; j < 8; ++j) {
        float xv = bf2f((unsigned short)bfr[ks][j]);
        bfr[ks][j] = (short)f2bf(fmaxf(fmaf(nsc[f0 + j], xv, nbt[f0 + j]), 0.f));
      }
    }
  }
  float bv[2] = {bias[colBase + l16], bias[colBase + 16 + l16]};
  float bvR[2] = {0.f, 0.f};
  if (!L2) { bvR[0] = bres[colBase + l16]; bvR[1] = bres[colBase + 16 + l16]; }
  float p1[2] = {0.f, 0.f}, p2[2] = {0.f, 0.f};

#pragma unroll
  for (int c2 = 0; c2 < 2; ++c2) {
    int col = colBase + c2 * 16 + l16;
    f32x4 acc = (f32x4){0.f, 0.f, 0.f, 0.f};
    f32x4 accR = (f32x4){0.f, 0.f, 0.f, 0.f};
#pragma unroll
    for (int ks = 0; ks < 4; ++ks) {
      bf16x8 w1 = *((const bf16x8*)&W1[col * 128 + ks * 32 + quad * 8]);
      bf16x8 w2 = *((const bf16x8*)&W2[col * 128 + ks * 32 + quad * 8]);
      acc = __builtin_amdgcn_mfma_f32_16x16x32_bf16(af[ks], w1, acc, 0, 0, 0);
      acc = __builtin_amdgcn_mfma_f32_16x16x32_bf16(bfr[ks], w2, acc, 0, 0, 0);
      if (!L2) {
        bf16x8 wr = *((const bf16x8*)&Wres[col * 128 + ks * 32 + quad * 8]);
        accR = __builtin_amdgcn_mfma_f32_16x16x32_bf16(bfr[ks], wr, accR, 0, 0, 0);
      }
    }
#pragma unroll
    for (int g = 0; g < 4; ++g) {
      int row = tile * 16 + quad * 4 + g;
      float v = acc[g] + bv[c2];
      outv[row * 128 + col] = f2bf(v);
      p1[c2] += v;
      p2[c2] += v * v;
      if (!L2) outres[row * 128 + col] = f2bf(accR[g] + bvR[c2]);
    }
  }

#pragma unroll
  for (int c2 = 0; c2 < 2; ++c2) {
    p1[c2] += __shfl_xor(p1[c2], 16); p1[c2] += __shfl_xor(p1[c2], 32);
    p2[c2] += __shfl_xor(p2[c2], 16); p2[c2] += __shfl_xor(p2[c2], 32);
  }
  if (quad == 0) {
#pragma unroll
    for (int c2 = 0; c2 < 2; ++c2) {
      sred[0][colBase + c2 * 16 + l16] = p1[c2];
      sred[1][colBase + c2 * 16 + l16] = p2[c2];
    }
  }
  __syncthreads();
  if (tid < 128) atomicAdd(&S[tid], sred[0][tid]);
  else atomicAdd(&S[tid], sred[1][tid - 128]);
}

// ---- final GraphNorm + ReLU + bf16 residual -> fp32, vectorized ---------
__global__ __launch_bounds__(256) void k_norm2(const unsigned short* __restrict__ pre,
                                               const float* __restrict__ S,
                                               const float* __restrict__ w,
                                               const float* __restrict__ b,
                                               const float* __restrict__ a,
                                               const unsigned short* __restrict__ res,
                                               float* __restrict__ outp) {
  int tr = blockIdx.x * 256 + threadIdx.x;
  int s16 = tr & 15;  // invariant under grid stride (stride % 16 == 0)
  const float invN = 1.0f / (float)N_NODES;
  float scv[8], btv[8];
#pragma unroll
  for (int i = 0; i < 8; ++i) {
    int f = s16 * 8 + i;
    float m = S[f] * invN;
    float ex2 = S[128 + f] * invN;
    float af = a[f];
    float var = fmaxf(ex2 - (2.f * af - af * af) * m * m, 0.f);
    float rstd = rsqrtf(var + 1e-5f);
    scv[i] = w[f] * rstd;
    btv[i] = b[f] - scv[i] * af * m;
  }
  const uint4* pp = (const uint4*)pre;
  const uint4* rp = (const uint4*)res;
  float4* op = (float4*)outp;
  for (int idx = tr; idx < N_NODES * 16; idx += gridDim.x * 256) {
    uint4 v = pp[idx];
    uint4 rr = rp[idx];
    const unsigned* pv = (const unsigned*)&v;
    const unsigned* pr = (const unsigned*)&rr;
    float o[8];
#pragma unroll
    for (int h = 0; h < 4; ++h) {
      float lo = bf2f((unsigned short)(pv[h] & 0xffffu));
      float hi = bf2f((unsigned short)(pv[h] >> 16));
      float rl = bf2f((unsigned short)(pr[h] & 0xffffu));
      float rh = bf2f((unsigned short)(pr[h] >> 16));
      o[2 * h] = fmaxf(fmaf(scv[2 * h], lo, btv[2 * h]), 0.f) + rl;
      o[2 * h + 1] = fmaxf(fmaf(scv[2 * h + 1], hi, btv[2 * h + 1]), 0.f) + rh;
    }
    op[idx * 2] = make_float4(o[0], o[1], o[2], o[3]);
    op[idx * 2 + 1] = make_float4(o[4], o[5], o[6], o[7]);
  }
}

extern "C" void kernel_launch(void* const* d_in, const int* in_sizes, int n_in,
                              void* d_out, int out_size, void* d_ws, size_t ws_size,
                              hipStream_t stream) {
  const float* x = (const float*)d_in[0];
  const int* ei = (const int*)d_in[1];
  const float* Wl1 = (const float*)d_in[2];
  const float* bl1 = (const float*)d_in[3];
  const float* Wr1 = (const float*)d_in[4];
  const float* Wl2 = (const float*)d_in[5];
  const float* bl2 = (const float*)d_in[6];
  const float* Wr2 = (const float*)d_in[7];
  const float* g1w = (const float*)d_in[8];
  const float* g1b = (const float*)d_in[9];
  const float* g1a = (const float*)d_in[10];
  const float* g2w = (const float*)d_in[11];
  const float* g2b = (const float*)d_in[12];
  const float* g2a = (const float*)d_in[13];
  const float* Wres = (const float*)d_in[14];
  const float* bres = (const float*)d_in[15];

  char* w = (char*)d_ws;
  const size_t FEATB = (size_t)N_NODES * D * 2;  // 12.8 MB bf16 buffer
  unsigned short* xb = (unsigned short*)(w);      // x bf16; reused as gemm2 out
  unsigned short* buf0 = (unsigned short*)(w + FEATB);
  unsigned short* scratch = (unsigned short*)(w + 2 * FEATB);  // binned only
  unsigned short* resb = (unsigned short*)(w + 3 * FEATB);
  char* ip = w + 4 * FEATB;
  float* stats = (float*)ip;                              // 2048 B
  int* cursor = (int*)(ip + 2064);                        // 512 B
  int* off = (int*)(ip + 2576);                           // 98*513*4 = 201096 B
  unsigned short* srcs = (unsigned short*)(ip + 203672);  // 3211264 B
  unsigned short* wb = (unsigned short*)(ip + 3414936);   // 163840 B
  const size_t NEED = 4 * FEATB + 3578776;
  unsigned int* binned = (unsigned int*)scratch;

  float* outp = (float*)d_out;

  if (ws_size < NEED) {  // diagnostic: finite wrong answer instead of NaN
    hipMemsetAsync(d_out, 0, (size_t)out_size * 4, stream);
    return;
  }

  unsigned short* wl1b = wb;
  unsigned short* wr1b = wb + 16384;
  unsigned short* wl2b = wb + 32768;
  unsigned short* wr2b = wb + 49152;
  unsigned short* wresb = wb + 65536;

  hipMemsetAsync(ip, 0, 2576, stream);

  k_prep<<<BIN_BLOCKS + 6330, 256, 0, stream>>>(x, Wl1, Wr1, Wl2, Wr2, Wres, xb, wb,
                                                ei, cursor, binned);
  k_pass2<<<NBKT, 512, 0, stream>>>(cursor, binned, off, srcs);

  // layer 1: fused agg+GEMM (+residual GEMM + stats)
  k_fused<false><<<NTILES, 256, 0, stream>>>(xb, off, srcs, wl1b, wr1b, wresb,
                                             bl1, bres, buf0, resb, stats,
                                             nullptr, nullptr, nullptr, nullptr);
  // layer 2: fused norm+agg+GEMM (+stats); writes xb (dead after layer 1)
  k_fused<true><<<NTILES, 256, 0, stream>>>(buf0, off, srcs, wl2b, wr2b, nullptr,
                                            bl2, nullptr, xb, nullptr, stats + 256,
                                            stats, g1w, g1b, g1a);
  k_norm2<<<1024, 256, 0, stream>>>(xb, stats + 256, g2w, g2b, g2a, resb, outp);
}

// Round 7
// 267.374 us; speedup vs baseline: 2.8190x; 1.3272x over previous
//
#include <hip/hip_runtime.h>

#define N_NODES 50000
#define N_EDGES 800000
#define D 128
#define NBKT 98       // ceil(50000/512) buckets of 512 dst nodes
#define BKT_SHIFT 9
#define BKT_CAP 16384 // padded per-bucket capacity
#define BIN_BLOCKS 196
#define EPB2 4096     // edges per binning block (196 blocks)
#define NTILES 3125   // 50000 / 16 exactly
#define GG 512        // gemm grid: 2 blocks/CU, one even generation
#define NODE_BLKS 12500
#define AGG_PERSIST 2048  // 8 blocks/CU exactly resident

typedef __attribute__((ext_vector_type(8))) short bf16x8;
typedef __attribute__((ext_vector_type(4))) float f32x4;

__device__ __forceinline__ float bf2f(unsigned short u) {
  unsigned int v = ((unsigned int)u) << 16;
  return __uint_as_float(v);
}
__device__ __forceinline__ unsigned short f2bf(float f) {
  unsigned int u = __float_as_uint(f);
  unsigned int r = (u + 0x7fffu + ((u >> 16) & 1u)) >> 16;
  return (unsigned short)r;
}

__device__ __forceinline__ int edge_at(const int* ei, int idx, int is64) {
  return is64 ? ei[2 * idx] : ei[idx];
}

// ---- merged: edge binning (196 blocks, per-block dtype detect) + casts --
__global__ __launch_bounds__(256) void k_prep(const float* __restrict__ x,
                                              const float* __restrict__ w0,
                                              const float* __restrict__ w1,
                                              const float* __restrict__ w2,
                                              const float* __restrict__ w3,
                                              const float* __restrict__ w4,
                                              unsigned short* __restrict__ xb,
                                              unsigned short* __restrict__ wout,
                                              const int* __restrict__ ei,
                                              int* __restrict__ cursor,
                                              unsigned int* __restrict__ binned) {
  int b = blockIdx.x;
  if (b >= BIN_BLOCKS) {
    int bc = b - BIN_BLOCKS;
    const float* src;
    unsigned short* dst;
    int i;
    if (bc < 6250) {
      src = x; dst = xb; i = bc * 256 + threadIdx.x;
    } else {
      int b2 = bc - 6250;
      int m = b2 >> 4;
      i = (b2 & 15) * 256 + threadIdx.x;
      src = (m == 0) ? w0 : (m == 1) ? w1 : (m == 2) ? w2 : (m == 3) ? w3 : w4;
      dst = wout + m * 16384;
    }
    float4 v = ((const float4*)src)[i];
    ushort4 o;
    o.x = f2bf(v.x); o.y = f2bf(v.y); o.z = f2bf(v.z); o.w = f2bf(v.w);
    ((ushort4*)dst)[i] = o;
    return;
  }
  __shared__ int red[256];
  __shared__ int h[128];
  __shared__ int resv[128];
  int t = threadIdx.x;
  int start = b * EPB2;
  int end = min(start + EPB2, N_EDGES);
  int acc = 0;
  for (int k = start + t; k < end; k += 256) acc |= ei[2 * k + 1];
  red[t] = acc;
  if (t < 128) h[t] = 0;
  __syncthreads();
  for (int s2 = 128; s2 > 0; s2 >>= 1) {
    if (t < s2) red[t] |= red[t + s2];
    __syncthreads();
  }
  int is64 = (red[0] == 0) ? 1 : 0;
  for (int e = start + t; e < end; e += 256) {
    int d = edge_at(ei, N_EDGES + e, is64);
    if ((unsigned)d < N_NODES) atomicAdd(&h[d >> BKT_SHIFT], 1);
  }
  __syncthreads();
  if (t < NBKT) {
    resv[t] = h[t] ? (t * BKT_CAP + atomicAdd(&cursor[t], h[t])) : 0;
    h[t] = 0;
  }
  __syncthreads();
  for (int e = start + t; e < end; e += 256) {
    int d = edge_at(ei, N_EDGES + e, is64);
    int sv = edge_at(ei, e, is64);
    if ((unsigned)d < N_NODES && (unsigned)sv < N_NODES) {
      int bkt = d >> BKT_SHIFT;
      int r = atomicAdd(&h[bkt], 1);
      int pos = resv[bkt] + r;
      if (pos < (bkt + 1) * BKT_CAP) binned[pos] = (unsigned)sv | ((unsigned)d << 16);
    }
  }
}

// ---- per-bucket CSR: off (bucket-padded, stride 513) + srcs scatter -----
__global__ __launch_bounds__(512) void k_pass2(const int* __restrict__ cursor,
                                               const unsigned int* __restrict__ binned,
                                               int* __restrict__ off,
                                               unsigned short* __restrict__ srcs) {
  __shared__ int h[512];
  __shared__ int sc[512];
  __shared__ int sx[512];
  int t = threadIdx.x;
  int b = blockIdx.x;
  int base = b * BKT_CAP;
  int cnt = min(cursor[b], BKT_CAP);
  h[t] = 0;
  __syncthreads();
  for (int e = base + t; e < base + cnt; e += 512) {
    unsigned v = binned[e];
    atomicAdd(&h[(int)(v >> 16) - (b << BKT_SHIFT)], 1);
  }
  __syncthreads();
  int mine = h[t];
  sc[t] = mine;
  __syncthreads();
  for (int s = 1; s < 512; s <<= 1) {
    int add = (t >= s) ? sc[t - s] : 0;
    __syncthreads();
    sc[t] += add;
    __syncthreads();
  }
  int excl = sc[t] - mine;
  sx[t] = excl;
  off[b * 513 + t] = base + excl;
  if (t == 0) off[b * 513 + 512] = base + cnt;
  h[t] = 0;
  __syncthreads();
  for (int e = base + t; e < base + cnt; e += 512) {
    unsigned v = binned[e];
    int l = (int)(v >> 16) - (b << BKT_SHIFT);
    int r = atomicAdd(&h[l], 1);
    srcs[base + sx[l] + r] = (unsigned short)(v & 0xffffu);
  }
}

// ---- mean aggregation (R0-proven scalar accumulate) ---------------------
template <bool NORM>
__device__ __forceinline__ void accum8(float* a, uint4 v, const float* sc,
                                       const float* bt) {
  const unsigned int* pv = (const unsigned int*)&v;
#pragma unroll
  for (int h = 0; h < 4; ++h) {
    float lo = bf2f((unsigned short)(pv[h] & 0xffffu));
    float hi = bf2f((unsigned short)(pv[h] >> 16));
    if (NORM) {
      a[2 * h] += fmaxf(fmaf(sc[2 * h], lo, bt[2 * h]), 0.f);
      a[2 * h + 1] += fmaxf(fmaf(sc[2 * h + 1], hi, bt[2 * h + 1]), 0.f);
    } else {
      a[2 * h] += lo;
      a[2 * h + 1] += hi;
    }
  }
}

// Grid-strided node loop: with grid=NODE_BLKS it executes exactly once per
// wave (identical to R0 form); with grid=AGG_PERSIST waves are persistent.
template <bool NORM>
__global__ __launch_bounds__(256) void k_agg(const unsigned short* __restrict__ feat,
                                             const int* __restrict__ off,
                                             const unsigned short* __restrict__ srcs,
                                             const float* __restrict__ Sin,
                                             const float* __restrict__ gw,
                                             const float* __restrict__ gb,
                                             const float* __restrict__ ga,
                                             unsigned short* __restrict__ agg) {
  int wv = threadIdx.x >> 6;
  int lane = threadIdx.x & 63;
  int q = lane >> 4, s = lane & 15;

  float sc[8], bt[8];
  if (NORM) {
    const float invN = 1.0f / (float)N_NODES;
#pragma unroll
    for (int i = 0; i < 8; ++i) {
      int f = s * 8 + i;
      float m = Sin[f] * invN;
      float ex2 = Sin[128 + f] * invN;
      float af = ga[f];
      float var = fmaxf(ex2 - (2.f * af - af * af) * m * m, 0.f);
      float rstd = rsqrtf(var + 1e-5f);
      sc[i] = gw[f] * rstd;
      bt[i] = gb[f] - sc[i] * af * m;
    }
  }

  const uint4* fp = (const uint4*)feat;
  for (int node = blockIdx.x * 4 + wv; node < N_NODES; node += gridDim.x * 4) {
    int oidx = (node >> BKT_SHIFT) * 513 + (node & 511);
    int b = off[oidx], e = off[oidx + 1];
    float a[8] = {0.f, 0.f, 0.f, 0.f, 0.f, 0.f, 0.f, 0.f};
    for (int cb = b; cb < e; cb += 64) {
      int n = min(64, e - cb);
      int jv = (lane < n) ? (int)srcs[cb + lane] : 0;
      int kmax = (n + 3) >> 2;
      int k = 0;
      for (; k + 2 <= kmax; k += 2) {
        int t0 = 4 * k + q;
        int t1 = t0 + 4;
        int j0 = __shfl(jv, t0);
        int j1 = __shfl(jv, t1);
        uint4 v0 = fp[j0 * 16 + s];
        uint4 v1 = fp[j1 * 16 + s];
        if (t0 < n) accum8<NORM>(a, v0, sc, bt);
        if (t1 < n) accum8<NORM>(a, v1, sc, bt);
      }
      if (k < kmax) {
        int t0 = 4 * k + q;
        int j0 = __shfl(jv, t0);
        uint4 v0 = fp[j0 * 16 + s];
        if (t0 < n) accum8<NORM>(a, v0, sc, bt);
      }
    }
#pragma unroll
    for (int i = 0; i < 8; ++i) {
      a[i] += __shfl_xor(a[i], 16);
      a[i] += __shfl_xor(a[i], 32);
    }
    if (q == 0) {
      float inv = 1.0f / (float)max(e - b, 1);
      uint4 o;
      o.x = (unsigned)f2bf(a[0] * inv) | ((unsigned)f2bf(a[1] * inv) << 16);
      o.y = (unsigned)f2bf(a[2] * inv) | ((unsigned)f2bf(a[3] * inv) << 16);
      o.z = (unsigned)f2bf(a[4] * inv) | ((unsigned)f2bf(a[5] * inv) << 16);
      o.w = (unsigned)f2bf(a[6] * inv) | ((unsigned)f2bf(a[7] * inv) << 16);
      ((uint4*)agg)[node * 16 + s] = o;
    }
  }
}

// ---- weight-stationary fused GEMM, 2-tile unrolled, atomic stats --------
template <bool FUSERES, bool NORMB>
__global__ __launch_bounds__(256) void k_gemm(const unsigned short* __restrict__ A,
                                              const unsigned short* __restrict__ B,
                                              const unsigned short* __restrict__ W1,
                                              const unsigned short* __restrict__ W2,
                                              const unsigned short* __restrict__ Wres,
                                              const float* __restrict__ bias,
                                              const float* __restrict__ bres,
                                              unsigned short* __restrict__ outv,
                                              unsigned short* __restrict__ outres,
                                              float* __restrict__ S,
                                              const float* __restrict__ Sin,
                                              const float* __restrict__ gw,
                                              const float* __restrict__ gb,
                                              const float* __restrict__ ga) {
  __shared__ float sred[2][128];
  __shared__ float nsc[128], nbt[128];
  const int tid = threadIdx.x;
  const int lane = tid & 63;
  const int wv = tid >> 6;
  const int quad = lane >> 4;
  const int l16 = lane & 15;
  const int colBase = wv * 32;

  if (NORMB) {
    if (tid < 128) {
      const float invN = 1.0f / (float)N_NODES;
      float m = Sin[tid] * invN;
      float ex2 = Sin[128 + tid] * invN;
      float af = ga[tid];
      float var = fmaxf(ex2 - (2.f * af - af * af) * m * m, 0.f);
      float rstd = rsqrtf(var + 1e-5f);
      float scv = gw[tid] * rstd;
      nsc[tid] = scv;
      nbt[tid] = gb[tid] - scv * af * m;
    }
    __syncthreads();
  }

  bf16x8 w1f[2][4], w2f[2][4], wrf[2][4];
  float bv[2], bvR[2];
#pragma unroll
  for (int c2 = 0; c2 < 2; ++c2) {
    int col = colBase + c2 * 16 + l16;
    bv[c2] = bias[col];
    if (FUSERES) bvR[c2] = bres[col];
#pragma unroll
    for (int ks = 0; ks < 4; ++ks) {
      w1f[c2][ks] = *((const bf16x8*)&W1[col * 128 + ks * 32 + quad * 8]);
      w2f[c2][ks] = *((const bf16x8*)&W2[col * 128 + ks * 32 + quad * 8]);
      if (FUSERES) wrf[c2][ks] = *((const bf16x8*)&Wres[col * 128 + ks * 32 + quad * 8]);
    }
  }

  float p1[2] = {0.f, 0.f}, p2[2] = {0.f, 0.f};

  for (int t0 = 2 * blockIdx.x; t0 < NTILES - 1; t0 += 2 * gridDim.x) {
    bf16x8 af[2][4], bfr[2][4];
#pragma unroll
    for (int u = 0; u < 2; ++u) {
      int arow = (t0 + u) * 16 + l16;
#pragma unroll
      for (int ks = 0; ks < 4; ++ks) {
        af[u][ks] = *((const bf16x8*)&A[arow * 128 + ks * 32 + quad * 8]);
        bfr[u][ks] = *((const bf16x8*)&B[arow * 128 + ks * 32 + quad * 8]);
      }
    }
    if (NORMB) {
#pragma unroll
      for (int u = 0; u < 2; ++u)
#pragma unroll
        for (int ks = 0; ks < 4; ++ks) {
          int f0 = ks * 32 + quad * 8;
#pragma unroll
          for (int j = 0; j < 8; ++j) {
            float xv = bf2f((unsigned short)bfr[u][ks][j]);
            bfr[u][ks][j] = (short)f2bf(fmaxf(fmaf(nsc[f0 + j], xv, nbt[f0 + j]), 0.f));
          }
        }
    }
    f32x4 acc[2][2], accR[2][2];
#pragma unroll
    for (int u = 0; u < 2; ++u)
#pragma unroll
      for (int c2 = 0; c2 < 2; ++c2) {
        acc[u][c2] = (f32x4){0.f, 0.f, 0.f, 0.f};
        if (FUSERES) accR[u][c2] = (f32x4){0.f, 0.f, 0.f, 0.f};
      }
#pragma unroll
    for (int u = 0; u < 2; ++u)
#pragma unroll
      for (int c2 = 0; c2 < 2; ++c2)
#pragma unroll
        for (int ks = 0; ks < 4; ++ks) {
          acc[u][c2] = __builtin_amdgcn_mfma_f32_16x16x32_bf16(af[u][ks], w1f[c2][ks], acc[u][c2], 0, 0, 0);
          acc[u][c2] = __builtin_amdgcn_mfma_f32_16x16x32_bf16(bfr[u][ks], w2f[c2][ks], acc[u][c2], 0, 0, 0);
          if (FUSERES)
            accR[u][c2] = __builtin_amdgcn_mfma_f32_16x16x32_bf16(bfr[u][ks], wrf[c2][ks], accR[u][c2], 0, 0, 0);
        }
#pragma unroll
    for (int u = 0; u < 2; ++u)
#pragma unroll
      for (int c2 = 0; c2 < 2; ++c2) {
        int col = colBase + c2 * 16 + l16;
#pragma unroll
        for (int g = 0; g < 4; ++g) {
          int row = (t0 + u) * 16 + quad * 4 + g;
          float v = acc[u][c2][g] + bv[c2];
          outv[row * 128 + col] = f2bf(v);
          p1[c2] += v;
          p2[c2] += v * v;
          if (FUSERES) outres[row * 128 + col] = f2bf(accR[u][c2][g] + bvR[c2]);
        }
      }
  }

  if (blockIdx.x == gridDim.x - 1) {  // tail tile 3124
    const int tile = NTILES - 1;
    int arow = tile * 16 + l16;
    bf16x8 af[4], bfr[4];
#pragma unroll
    for (int ks = 0; ks < 4; ++ks) {
      af[ks] = *((const bf16x8*)&A[arow * 128 + ks * 32 + quad * 8]);
      bfr[ks] = *((const bf16x8*)&B[arow * 128 + ks * 32 + quad * 8]);
    }
    if (NORMB) {
#pragma unroll
      for (int ks = 0; ks < 4; ++ks) {
        int f0 = ks * 32 + quad * 8;
#pragma unroll
        for (int j = 0; j < 8; ++j) {
          float xv = bf2f((unsigned short)bfr[ks][j]);
          bfr[ks][j] = (short)f2bf(fmaxf(fmaf(nsc[f0 + j], xv, nbt[f0 + j]), 0.f));
        }
      }
    }
    f32x4 acc[2], accR[2];
#pragma unroll
    for (int c2 = 0; c2 < 2; ++c2) {
      acc[c2] = (f32x4){0.f, 0.f, 0.f, 0.f};
      if (FUSERES) accR[c2] = (f32x4){0.f, 0.f, 0.f, 0.f};
    }
#pragma unroll
    for (int c2 = 0; c2 < 2; ++c2)
#pragma unroll
      for (int ks = 0; ks < 4; ++ks) {
        acc[c2] = __builtin_amdgcn_mfma_f32_16x16x32_bf16(af[ks], w1f[c2][ks], acc[c2], 0, 0, 0);
        acc[c2] = __builtin_amdgcn_mfma_f32_16x16x32_bf16(bfr[ks], w2f[c2][ks], acc[c2], 0, 0, 0);
        if (FUSERES)
          accR[c2] = __builtin_amdgcn_mfma_f32_16x16x32_bf16(bfr[ks], wrf[c2][ks], accR[c2], 0, 0, 0);
      }
#pragma unroll
    for (int c2 = 0; c2 < 2; ++c2) {
      int col = colBase + c2 * 16 + l16;
#pragma unroll
      for (int g = 0; g < 4; ++g) {
        int row = tile * 16 + quad * 4 + g;
        float v = acc[c2][g] + bv[c2];
        outv[row * 128 + col] = f2bf(v);
        p1[c2] += v;
        p2[c2] += v * v;
        if (FUSERES) outres[row * 128 + col] = f2bf(accR[c2][g] + bvR[c2]);
      }
    }
  }

#pragma unroll
  for (int c2 = 0; c2 < 2; ++c2) {
    p1[c2] += __shfl_xor(p1[c2], 16); p1[c2] += __shfl_xor(p1[c2], 32);
    p2[c2] += __shfl_xor(p2[c2], 16); p2[c2] += __shfl_xor(p2[c2], 32);
  }
  if (quad == 0) {
#pragma unroll
    for (int c2 = 0; c2 < 2; ++c2) {
      sred[0][colBase + c2 * 16 + l16] = p1[c2];
      sred[1][colBase + c2 * 16 + l16] = p2[c2];
    }
  }
  __syncthreads();
  if (tid < 128) atomicAdd(&S[tid], sred[0][tid]);
  else atomicAdd(&S[tid], sred[1][tid - 128]);
}

// ---- final GraphNorm + ReLU + bf16 residual -> fp32, vectorized ---------
__global__ __launch_bounds__(256) void k_norm2(const unsigned short* __restrict__ pre,
                                               const float* __restrict__ S,
                                               const float* __restrict__ w,
                                               const float* __restrict__ b,
                                               const float* __restrict__ a,
                                               const unsigned short* __restrict__ res,
                                               float* __restrict__ outp) {
  int tr = blockIdx.x * 256 + threadIdx.x;
  int s16 = tr & 15;  // invariant under grid stride (stride % 16 == 0)
  const float invN = 1.0f / (float)N_NODES;
  float scv[8], btv[8];
#pragma unroll
  for (int i = 0; i < 8; ++i) {
    int f = s16 * 8 + i;
    float m = S[f] * invN;
    float ex2 = S[128 + f] * invN;
    float af = a[f];
    float var = fmaxf(ex2 - (2.f * af - af * af) * m * m, 0.f);
    float rstd = rsqrtf(var + 1e-5f);
    scv[i] = w[f] * rstd;
    btv[i] = b[f] - scv[i] * af * m;
  }
  const uint4* pp = (const uint4*)pre;
  const uint4* rp = (const uint4*)res;
  float4* op = (float4*)outp;
  for (int idx = tr; idx < N_NODES * 16; idx += gridDim.x * 256) {
    uint4 v = pp[idx];
    uint4 rr = rp[idx];
    const unsigned* pv = (const unsigned*)&v;
    const unsigned* pr = (const unsigned*)&rr;
    float o[8];
#pragma unroll
    for (int h = 0; h < 4; ++h) {
      float lo = bf2f((unsigned short)(pv[h] & 0xffffu));
      float hi = bf2f((unsigned short)(pv[h] >> 16));
      float rl = bf2f((unsigned short)(pr[h] & 0xffffu));
      float rh = bf2f((unsigned short)(pr[h] >> 16));
      o[2 * h] = fmaxf(fmaf(scv[2 * h], lo, btv[2 * h]), 0.f) + rl;
      o[2 * h + 1] = fmaxf(fmaf(scv[2 * h + 1], hi, btv[2 * h + 1]), 0.f) + rh;
    }
    op[idx * 2] = make_float4(o[0], o[1], o[2], o[3]);
    op[idx * 2 + 1] = make_float4(o[4], o[5], o[6], o[7]);
  }
}

extern "C" void kernel_launch(void* const* d_in, const int* in_sizes, int n_in,
                              void* d_out, int out_size, void* d_ws, size_t ws_size,
                              hipStream_t stream) {
  const float* x = (const float*)d_in[0];
  const int* ei = (const int*)d_in[1];
  const float* Wl1 = (const float*)d_in[2];
  const float* bl1 = (const float*)d_in[3];
  const float* Wr1 = (const float*)d_in[4];
  const float* Wl2 = (const float*)d_in[5];
  const float* bl2 = (const float*)d_in[6];
  const float* Wr2 = (const float*)d_in[7];
  const float* g1w = (const float*)d_in[8];
  const float* g1b = (const float*)d_in[9];
  const float* g1a = (const float*)d_in[10];
  const float* g2w = (const float*)d_in[11];
  const float* g2b = (const float*)d_in[12];
  const float* g2a = (const float*)d_in[13];
  const float* Wres = (const float*)d_in[14];
  const float* bres = (const float*)d_in[15];

  char* w = (char*)d_ws;
  const size_t FEATB = (size_t)N_NODES * D * 2;  // 12.8 MB bf16 buffer
  unsigned short* xb = (unsigned short*)(w);      // x bf16; reused as gemm2 out
  unsigned short* buf0 = (unsigned short*)(w + FEATB);
  unsigned short* agg = (unsigned short*)(w + 2 * FEATB);
  unsigned short* resb = (unsigned short*)(w + 3 * FEATB);
  char* ip = w + 4 * FEATB;
  float* stats = (float*)ip;                              // 2048 B
  int* cursor = (int*)(ip + 2064);                        // 512 B
  int* off = (int*)(ip + 2576);                           // 98*513*4 = 201096 B
  unsigned short* srcs = (unsigned short*)(ip + 203672);  // 3211264 B
  unsigned short* wb = (unsigned short*)(ip + 3414936);   // 163840 B
  const size_t NEED = 4 * FEATB + 3578776;
  unsigned int* binned = (unsigned int*)agg;  // alias; pre-agg use only

  float* outp = (float*)d_out;

  if (ws_size < NEED) {  // diagnostic: finite wrong answer instead of NaN
    hipMemsetAsync(d_out, 0, (size_t)out_size * 4, stream);
    return;
  }

  unsigned short* wl1b = wb;
  unsigned short* wr1b = wb + 16384;
  unsigned short* wl2b = wb + 32768;
  unsigned short* wr2b = wb + 49152;
  unsigned short* wresb = wb + 65536;

  hipMemsetAsync(ip, 0, 2576, stream);

  k_prep<<<BIN_BLOCKS + 6330, 256, 0, stream>>>(x, Wl1, Wr1, Wl2, Wr2, Wres, xb, wb,
                                                ei, cursor, binned);
  k_pass2<<<NBKT, 512, 0, stream>>>(cursor, binned, off, srcs);

  // layer 1: one node per wave, 12500 blocks (R0-proven)
  k_agg<false><<<NODE_BLKS, 256, 0, stream>>>(xb, off, srcs, nullptr, nullptr,
                                              nullptr, nullptr, agg);
  k_gemm<true, false><<<GG, 256, 0, stream>>>(agg, xb, wl1b, wr1b, wresb, bl1, bres,
                                              buf0, resb, stats,
                                              nullptr, nullptr, nullptr, nullptr);

  // layer 2: persistent grid-stride, 2048 blocks (8/CU) — proven neutral
  k_agg<true><<<AGG_PERSIST, 256, 0, stream>>>(buf0, off, srcs, stats, g1w, g1b,
                                               g1a, agg);
  k_gemm<false, true><<<GG, 256, 0, stream>>>(agg, buf0, wl2b, wr2b, nullptr, bl2,
                                              nullptr, xb, nullptr, stats + 256,
                                              stats, g1w, g1b, g1a);
  k_norm2<<<1024, 256, 0, stream>>>(xb, stats + 256, g2w, g2b, g2a, resb, outp);
}

// Round 8
// 264.669 us; speedup vs baseline: 2.8478x; 1.0102x over previous
//
#include <hip/hip_runtime.h>

#define N_NODES 50000
#define N_EDGES 800000
#define D 128
#define NBKT 98       // ceil(50000/512) buckets of 512 dst nodes
#define BKT_SHIFT 9
#define BKT_CAP 16384 // padded per-bucket capacity
#define BIN_BLOCKS 196
#define EPB2 4096     // edges per binning block (196 blocks)
#define NTILES 3125   // 50000 / 16 exactly
#define GG 512        // gemm grid: 2 blocks/CU, one even generation
#define NODE_BLKS 12500
#define AGG_PERSIST 2048  // 8 blocks/CU exactly resident

typedef __attribute__((ext_vector_type(8))) short bf16x8;
typedef __attribute__((ext_vector_type(4))) float f32x4;

__device__ __forceinline__ float bf2f(unsigned short u) {
  unsigned int v = ((unsigned int)u) << 16;
  return __uint_as_float(v);
}
__device__ __forceinline__ unsigned short f2bf(float f) {
  unsigned int u = __float_as_uint(f);
  unsigned int r = (u + 0x7fffu + ((u >> 16) & 1u)) >> 16;
  return (unsigned short)r;
}

__device__ __forceinline__ int edge_at(const int* ei, int idx, int is64) {
  return is64 ? ei[2 * idx] : ei[idx];
}

// ---- merged: edge binning (196 blocks, per-block dtype detect) + casts --
__global__ __launch_bounds__(256) void k_prep(const float* __restrict__ x,
                                              const float* __restrict__ w0,
                                              const float* __restrict__ w1,
                                              const float* __restrict__ w2,
                                              const float* __restrict__ w3,
                                              const float* __restrict__ w4,
                                              unsigned short* __restrict__ xb,
                                              unsigned short* __restrict__ wout,
                                              const int* __restrict__ ei,
                                              int* __restrict__ cursor,
                                              unsigned int* __restrict__ binned) {
  int b = blockIdx.x;
  if (b >= BIN_BLOCKS) {
    int bc = b - BIN_BLOCKS;
    const float* src;
    unsigned short* dst;
    int i;
    if (bc < 6250) {
      src = x; dst = xb; i = bc * 256 + threadIdx.x;
    } else {
      int b2 = bc - 6250;
      int m = b2 >> 4;
      i = (b2 & 15) * 256 + threadIdx.x;
      src = (m == 0) ? w0 : (m == 1) ? w1 : (m == 2) ? w2 : (m == 3) ? w3 : w4;
      dst = wout + m * 16384;
    }
    float4 v = ((const float4*)src)[i];
    ushort4 o;
    o.x = f2bf(v.x); o.y = f2bf(v.y); o.z = f2bf(v.z); o.w = f2bf(v.w);
    ((ushort4*)dst)[i] = o;
    return;
  }
  __shared__ int red[256];
  __shared__ int h[128];
  __shared__ int resv[128];
  int t = threadIdx.x;
  int start = b * EPB2;
  int end = min(start + EPB2, N_EDGES);
  int acc = 0;
  for (int k = start + t; k < end; k += 256) acc |= ei[2 * k + 1];
  red[t] = acc;
  if (t < 128) h[t] = 0;
  __syncthreads();
  for (int s2 = 128; s2 > 0; s2 >>= 1) {
    if (t < s2) red[t] |= red[t + s2];
    __syncthreads();
  }
  int is64 = (red[0] == 0) ? 1 : 0;
  for (int e = start + t; e < end; e += 256) {
    int d = edge_at(ei, N_EDGES + e, is64);
    if ((unsigned)d < N_NODES) atomicAdd(&h[d >> BKT_SHIFT], 1);
  }
  __syncthreads();
  if (t < NBKT) {
    resv[t] = h[t] ? (t * BKT_CAP + atomicAdd(&cursor[t], h[t])) : 0;
    h[t] = 0;
  }
  __syncthreads();
  for (int e = start + t; e < end; e += 256) {
    int d = edge_at(ei, N_EDGES + e, is64);
    int sv = edge_at(ei, e, is64);
    if ((unsigned)d < N_NODES && (unsigned)sv < N_NODES) {
      int bkt = d >> BKT_SHIFT;
      int r = atomicAdd(&h[bkt], 1);
      int pos = resv[bkt] + r;
      if (pos < (bkt + 1) * BKT_CAP) binned[pos] = (unsigned)sv | ((unsigned)d << 16);
    }
  }
}

// ---- per-bucket CSR: wave-shfl scan (3 barriers instead of ~18) ---------
__global__ __launch_bounds__(512) void k_pass2(const int* __restrict__ cursor,
                                               const unsigned int* __restrict__ binned,
                                               int* __restrict__ off,
                                               unsigned short* __restrict__ srcs) {
  __shared__ int h[512];
  __shared__ int sx[512];
  __shared__ int wsum[8];
  int t = threadIdx.x;
  int b = blockIdx.x;
  int base = b * BKT_CAP;
  int cnt = min(cursor[b], BKT_CAP);
  h[t] = 0;
  __syncthreads();
  for (int e = base + t; e < base + cnt; e += 512) {
    unsigned v = binned[e];
    atomicAdd(&h[(int)(v >> 16) - (b << BKT_SHIFT)], 1);
  }
  __syncthreads();
  int mine = h[t];
  // per-wave inclusive scan via shfl_up (no barriers)
  int incl = mine;
#pragma unroll
  for (int d = 1; d < 64; d <<= 1) {
    int up = __shfl_up(incl, d);
    if ((t & 63) >= d) incl += up;
  }
  int w = t >> 6;
  if ((t & 63) == 63) wsum[w] = incl;
  h[t] = 0;  // reset for scatter ranks (pre-barrier; mine already read)
  __syncthreads();
  int woff = 0;
#pragma unroll
  for (int i = 0; i < 7; ++i) woff += (i < w) ? wsum[i] : 0;
  int excl = woff + incl - mine;
  sx[t] = excl;
  off[b * 513 + t] = base + excl;
  if (t == 0) off[b * 513 + 512] = base + cnt;
  __syncthreads();
  for (int e = base + t; e < base + cnt; e += 512) {
    unsigned v = binned[e];
    int l = (int)(v >> 16) - (b << BKT_SHIFT);
    int r = atomicAdd(&h[l], 1);
    srcs[base + sx[l] + r] = (unsigned short)(v & 0xffffu);
  }
}

// ---- mean aggregation (R0-proven scalar accumulate) ---------------------
template <bool NORM>
__device__ __forceinline__ void accum8(float* a, uint4 v, const float* sc,
                                       const float* bt) {
  const unsigned int* pv = (const unsigned int*)&v;
#pragma unroll
  for (int h = 0; h < 4; ++h) {
    float lo = bf2f((unsigned short)(pv[h] & 0xffffu));
    float hi = bf2f((unsigned short)(pv[h] >> 16));
    if (NORM) {
      a[2 * h] += fmaxf(fmaf(sc[2 * h], lo, bt[2 * h]), 0.f);
      a[2 * h + 1] += fmaxf(fmaf(sc[2 * h + 1], hi, bt[2 * h + 1]), 0.f);
    } else {
      a[2 * h] += lo;
      a[2 * h + 1] += hi;
    }
  }
}

// Grid-strided node loop: with grid=NODE_BLKS it executes exactly once per
// wave (identical to R0 form); with grid=AGG_PERSIST waves are persistent.
template <bool NORM>
__global__ __launch_bounds__(256) void k_agg(const unsigned short* __restrict__ feat,
                                             const int* __restrict__ off,
                                             const unsigned short* __restrict__ srcs,
                                             const float* __restrict__ Sin,
                                             const float* __restrict__ gw,
                                             const float* __restrict__ gb,
                                             const float* __restrict__ ga,
                                             unsigned short* __restrict__ agg) {
  int wv = threadIdx.x >> 6;
  int lane = threadIdx.x & 63;
  int q = lane >> 4, s = lane & 15;

  float sc[8], bt[8];
  if (NORM) {
    const float invN = 1.0f / (float)N_NODES;
#pragma unroll
    for (int i = 0; i < 8; ++i) {
      int f = s * 8 + i;
      float m = Sin[f] * invN;
      float ex2 = Sin[128 + f] * invN;
      float af = ga[f];
      float var = fmaxf(ex2 - (2.f * af - af * af) * m * m, 0.f);
      float rstd = rsqrtf(var + 1e-5f);
      sc[i] = gw[f] * rstd;
      bt[i] = gb[f] - sc[i] * af * m;
    }
  }

  const uint4* fp = (const uint4*)feat;
  for (int node = blockIdx.x * 4 + wv; node < N_NODES; node += gridDim.x * 4) {
    int oidx = (node >> BKT_SHIFT) * 513 + (node & 511);
    int b = off[oidx], e = off[oidx + 1];
    float a[8] = {0.f, 0.f, 0.f, 0.f, 0.f, 0.f, 0.f, 0.f};
    for (int cb = b; cb < e; cb += 64) {
      int n = min(64, e - cb);
      int jv = (lane < n) ? (int)srcs[cb + lane] : 0;
      int kmax = (n + 3) >> 2;
      int k = 0;
      for (; k + 2 <= kmax; k += 2) {
        int t0 = 4 * k + q;
        int t1 = t0 + 4;
        int j0 = __shfl(jv, t0);
        int j1 = __shfl(jv, t1);
        uint4 v0 = fp[j0 * 16 + s];
        uint4 v1 = fp[j1 * 16 + s];
        if (t0 < n) accum8<NORM>(a, v0, sc, bt);
        if (t1 < n) accum8<NORM>(a, v1, sc, bt);
      }
      if (k < kmax) {
        int t0 = 4 * k + q;
        int j0 = __shfl(jv, t0);
        uint4 v0 = fp[j0 * 16 + s];
        if (t0 < n) accum8<NORM>(a, v0, sc, bt);
      }
    }
#pragma unroll
    for (int i = 0; i < 8; ++i) {
      a[i] += __shfl_xor(a[i], 16);
      a[i] += __shfl_xor(a[i], 32);
    }
    if (q == 0) {
      float inv = 1.0f / (float)max(e - b, 1);
      uint4 o;
      o.x = (unsigned)f2bf(a[0] * inv) | ((unsigned)f2bf(a[1] * inv) << 16);
      o.y = (unsigned)f2bf(a[2] * inv) | ((unsigned)f2bf(a[3] * inv) << 16);
      o.z = (unsigned)f2bf(a[4] * inv) | ((unsigned)f2bf(a[5] * inv) << 16);
      o.w = (unsigned)f2bf(a[6] * inv) | ((unsigned)f2bf(a[7] * inv) << 16);
      ((uint4*)agg)[node * 16 + s] = o;
    }
  }
}

// ---- weight-stationary fused GEMM, 2-tile unrolled, atomic stats --------
template <bool FUSERES, bool NORMB>
__global__ __launch_bounds__(256) void k_gemm(const unsigned short* __restrict__ A,
                                              const unsigned short* __restrict__ B,
                                              const unsigned short* __restrict__ W1,
                                              const unsigned short* __restrict__ W2,
                                              const unsigned short* __restrict__ Wres,
                                              const float* __restrict__ bias,
                                              const float* __restrict__ bres,
                                              unsigned short* __restrict__ outv,
                                              unsigned short* __restrict__ outres,
                                              float* __restrict__ S,
                                              const float* __restrict__ Sin,
                                              const float* __restrict__ gw,
                                              const float* __restrict__ gb,
                                              const float* __restrict__ ga) {
  __shared__ float sred[2][128];
  __shared__ float nsc[128], nbt[128];
  const int tid = threadIdx.x;
  const int lane = tid & 63;
  const int wv = tid >> 6;
  const int quad = lane >> 4;
  const int l16 = lane & 15;
  const int colBase = wv * 32;

  if (NORMB) {
    if (tid < 128) {
      const float invN = 1.0f / (float)N_NODES;
      float m = Sin[tid] * invN;
      float ex2 = Sin[128 + tid] * invN;
      float af = ga[tid];
      float var = fmaxf(ex2 - (2.f * af - af * af) * m * m, 0.f);
      float rstd = rsqrtf(var + 1e-5f);
      float scv = gw[tid] * rstd;
      nsc[tid] = scv;
      nbt[tid] = gb[tid] - scv * af * m;
    }
    __syncthreads();
  }

  bf16x8 w1f[2][4], w2f[2][4], wrf[2][4];
  float bv[2], bvR[2];
#pragma unroll
  for (int c2 = 0; c2 < 2; ++c2) {
    int col = colBase + c2 * 16 + l16;
    bv[c2] = bias[col];
    if (FUSERES) bvR[c2] = bres[col];
#pragma unroll
    for (int ks = 0; ks < 4; ++ks) {
      w1f[c2][ks] = *((const bf16x8*)&W1[col * 128 + ks * 32 + quad * 8]);
      w2f[c2][ks] = *((const bf16x8*)&W2[col * 128 + ks * 32 + quad * 8]);
      if (FUSERES) wrf[c2][ks] = *((const bf16x8*)&Wres[col * 128 + ks * 32 + quad * 8]);
    }
  }

  float p1[2] = {0.f, 0.f}, p2[2] = {0.f, 0.f};

  for (int t0 = 2 * blockIdx.x; t0 < NTILES - 1; t0 += 2 * gridDim.x) {
    bf16x8 af[2][4], bfr[2][4];
#pragma unroll
    for (int u = 0; u < 2; ++u) {
      int arow = (t0 + u) * 16 + l16;
#pragma unroll
      for (int ks = 0; ks < 4; ++ks) {
        af[u][ks] = *((const bf16x8*)&A[arow * 128 + ks * 32 + quad * 8]);
        bfr[u][ks] = *((const bf16x8*)&B[arow * 128 + ks * 32 + quad * 8]);
      }
    }
    if (NORMB) {
#pragma unroll
      for (int u = 0; u < 2; ++u)
#pragma unroll
        for (int ks = 0; ks < 4; ++ks) {
          int f0 = ks * 32 + quad * 8;
#pragma unroll
          for (int j = 0; j < 8; ++j) {
            float xv = bf2f((unsigned short)bfr[u][ks][j]);
            bfr[u][ks][j] = (short)f2bf(fmaxf(fmaf(nsc[f0 + j], xv, nbt[f0 + j]), 0.f));
          }
        }
    }
    f32x4 acc[2][2], accR[2][2];
#pragma unroll
    for (int u = 0; u < 2; ++u)
#pragma unroll
      for (int c2 = 0; c2 < 2; ++c2) {
        acc[u][c2] = (f32x4){0.f, 0.f, 0.f, 0.f};
        if (FUSERES) accR[u][c2] = (f32x4){0.f, 0.f, 0.f, 0.f};
      }
#pragma unroll
    for (int u = 0; u < 2; ++u)
#pragma unroll
      for (int c2 = 0; c2 < 2; ++c2)
#pragma unroll
        for (int ks = 0; ks < 4; ++ks) {
          acc[u][c2] = __builtin_amdgcn_mfma_f32_16x16x32_bf16(af[u][ks], w1f[c2][ks], acc[u][c2], 0, 0, 0);
          acc[u][c2] = __builtin_amdgcn_mfma_f32_16x16x32_bf16(bfr[u][ks], w2f[c2][ks], acc[u][c2], 0, 0, 0);
          if (FUSERES)
            accR[u][c2] = __builtin_amdgcn_mfma_f32_16x16x32_bf16(bfr[u][ks], wrf[c2][ks], accR[u][c2], 0, 0, 0);
        }
#pragma unroll
    for (int u = 0; u < 2; ++u)
#pragma unroll
      for (int c2 = 0; c2 < 2; ++c2) {
        int col = colBase + c2 * 16 + l16;
#pragma unroll
        for (int g = 0; g < 4; ++g) {
          int row = (t0 + u) * 16 + quad * 4 + g;
          float v = acc[u][c2][g] + bv[c2];
          outv[row * 128 + col] = f2bf(v);
          p1[c2] += v;
          p2[c2] += v * v;
          if (FUSERES) outres[row * 128 + col] = f2bf(accR[u][c2][g] + bvR[c2]);
        }
      }
  }

  if (blockIdx.x == gridDim.x - 1) {  // tail tile 3124
    const int tile = NTILES - 1;
    int arow = tile * 16 + l16;
    bf16x8 af[4], bfr[4];
#pragma unroll
    for (int ks = 0; ks < 4; ++ks) {
      af[ks] = *((const bf16x8*)&A[arow * 128 + ks * 32 + quad * 8]);
      bfr[ks] = *((const bf16x8*)&B[arow * 128 + ks * 32 + quad * 8]);
    }
    if (NORMB) {
#pragma unroll
      for (int ks = 0; ks < 4; ++ks) {
        int f0 = ks * 32 + quad * 8;
#pragma unroll
        for (int j = 0; j < 8; ++j) {
          float xv = bf2f((unsigned short)bfr[ks][j]);
          bfr[ks][j] = (short)f2bf(fmaxf(fmaf(nsc[f0 + j], xv, nbt[f0 + j]), 0.f));
        }
      }
    }
    f32x4 acc[2], accR[2];
#pragma unroll
    for (int c2 = 0; c2 < 2; ++c2) {
      acc[c2] = (f32x4){0.f, 0.f, 0.f, 0.f};
      if (FUSERES) accR[c2] = (f32x4){0.f, 0.f, 0.f, 0.f};
    }
#pragma unroll
    for (int c2 = 0; c2 < 2; ++c2)
#pragma unroll
      for (int ks = 0; ks < 4; ++ks) {
        acc[c2] = __builtin_amdgcn_mfma_f32_16x16x32_bf16(af[ks], w1f[c2][ks], acc[c2], 0, 0, 0);
        acc[c2] = __builtin_amdgcn_mfma_f32_16x16x32_bf16(bfr[ks], w2f[c2][ks], acc[c2], 0, 0, 0);
        if (FUSERES)
          accR[c2] = __builtin_amdgcn_mfma_f32_16x16x32_bf16(bfr[ks], wrf[c2][ks], accR[c2], 0, 0, 0);
      }
#pragma unroll
    for (int c2 = 0; c2 < 2; ++c2) {
      int col = colBase + c2 * 16 + l16;
#pragma unroll
      for (int g = 0; g < 4; ++g) {
        int row = tile * 16 + quad * 4 + g;
        float v = acc[c2][g] + bv[c2];
        outv[row * 128 + col] = f2bf(v);
        p1[c2] += v;
        p2[c2] += v * v;
        if (FUSERES) outres[row * 128 + col] = f2bf(accR[c2][g] + bvR[c2]);
      }
    }
  }

#pragma unroll
  for (int c2 = 0; c2 < 2; ++c2) {
    p1[c2] += __shfl_xor(p1[c2], 16); p1[c2] += __shfl_xor(p1[c2], 32);
    p2[c2] += __shfl_xor(p2[c2], 16); p2[c2] += __shfl_xor(p2[c2], 32);
  }
  if (quad == 0) {
#pragma unroll
    for (int c2 = 0; c2 < 2; ++c2) {
      sred[0][colBase + c2 * 16 + l16] = p1[c2];
      sred[1][colBase + c2 * 16 + l16] = p2[c2];
    }
  }
  __syncthreads();
  if (tid < 128) atomicAdd(&S[tid], sred[0][tid]);
  else atomicAdd(&S[tid], sred[1][tid - 128]);
}

// ---- final GraphNorm + ReLU + bf16 residual -> fp32, vectorized ---------
__global__ __launch_bounds__(256) void k_norm2(const unsigned short* __restrict__ pre,
                                               const float* __restrict__ S,
                                               const float* __restrict__ w,
                                               const float* __restrict__ b,
                                               const float* __restrict__ a,
                                               const unsigned short* __restrict__ res,
                                               float* __restrict__ outp) {
  int tr = blockIdx.x * 256 + threadIdx.x;
  int s16 = tr & 15;  // invariant under grid stride (stride % 16 == 0)
  const float invN = 1.0f / (float)N_NODES;
  float scv[8], btv[8];
#pragma unroll
  for (int i = 0; i < 8; ++i) {
    int f = s16 * 8 + i;
    float m = S[f] * invN;
    float ex2 = S[128 + f] * invN;
    float af = a[f];
    float var = fmaxf(ex2 - (2.f * af - af * af) * m * m, 0.f);
    float rstd = rsqrtf(var + 1e-5f);
    scv[i] = w[f] * rstd;
    btv[i] = b[f] - scv[i] * af * m;
  }
  const uint4* pp = (const uint4*)pre;
  const uint4* rp = (const uint4*)res;
  float4* op = (float4*)outp;
  for (int idx = tr; idx < N_NODES * 16; idx += gridDim.x * 256) {
    uint4 v = pp[idx];
    uint4 rr = rp[idx];
    const unsigned* pv = (const unsigned*)&v;
    const unsigned* pr = (const unsigned*)&rr;
    float o[8];
#pragma unroll
    for (int h = 0; h < 4; ++h) {
      float lo = bf2f((unsigned short)(pv[h] & 0xffffu));
      float hi = bf2f((unsigned short)(pv[h] >> 16));
      float rl = bf2f((unsigned short)(pr[h] & 0xffffu));
      float rh = bf2f((unsigned short)(pr[h] >> 16));
      o[2 * h] = fmaxf(fmaf(scv[2 * h], lo, btv[2 * h]), 0.f) + rl;
      o[2 * h + 1] = fmaxf(fmaf(scv[2 * h + 1], hi, btv[2 * h + 1]), 0.f) + rh;
    }
    op[idx * 2] = make_float4(o[0], o[1], o[2], o[3]);
    op[idx * 2 + 1] = make_float4(o[4], o[5], o[6], o[7]);
  }
}

extern "C" void kernel_launch(void* const* d_in, const int* in_sizes, int n_in,
                              void* d_out, int out_size, void* d_ws, size_t ws_size,
                              hipStream_t stream) {
  const float* x = (const float*)d_in[0];
  const int* ei = (const int*)d_in[1];
  const float* Wl1 = (const float*)d_in[2];
  const float* bl1 = (const float*)d_in[3];
  const float* Wr1 = (const float*)d_in[4];
  const float* Wl2 = (const float*)d_in[5];
  const float* bl2 = (const float*)d_in[6];
  const float* Wr2 = (const float*)d_in[7];
  const float* g1w = (const float*)d_in[8];
  const float* g1b = (const float*)d_in[9];
  const float* g1a = (const float*)d_in[10];
  const float* g2w = (const float*)d_in[11];
  const float* g2b = (const float*)d_in[12];
  const float* g2a = (const float*)d_in[13];
  const float* Wres = (const float*)d_in[14];
  const float* bres = (const float*)d_in[15];

  char* w = (char*)d_ws;
  const size_t FEATB = (size_t)N_NODES * D * 2;  // 12.8 MB bf16 buffer
  unsigned short* xb = (unsigned short*)(w);      // x bf16; reused as gemm2 out
  unsigned short* buf0 = (unsigned short*)(w + FEATB);
  unsigned short* agg = (unsigned short*)(w + 2 * FEATB);
  unsigned short* resb = (unsigned short*)(w + 3 * FEATB);
  char* ip = w + 4 * FEATB;
  float* stats = (float*)ip;                              // 2048 B
  int* cursor = (int*)(ip + 2064);                        // 512 B
  int* off = (int*)(ip + 2576);                           // 98*513*4 = 201096 B
  unsigned short* srcs = (unsigned short*)(ip + 203672);  // 3211264 B
  unsigned short* wb = (unsigned short*)(ip + 3414936);   // 163840 B
  const size_t NEED = 4 * FEATB + 3578776;
  unsigned int* binned = (unsigned int*)agg;  // alias; pre-agg use only

  float* outp = (float*)d_out;

  if (ws_size < NEED) {  // diagnostic: finite wrong answer instead of NaN
    hipMemsetAsync(d_out, 0, (size_t)out_size * 4, stream);
    return;
  }

  unsigned short* wl1b = wb;
  unsigned short* wr1b = wb + 16384;
  unsigned short* wl2b = wb + 32768;
  unsigned short* wr2b = wb + 49152;
  unsigned short* wresb = wb + 65536;

  hipMemsetAsync(ip, 0, 2576, stream);

  k_prep<<<BIN_BLOCKS + 6330, 256, 0, stream>>>(x, Wl1, Wr1, Wl2, Wr2, Wres, xb, wb,
                                                ei, cursor, binned);
  k_pass2<<<NBKT, 512, 0, stream>>>(cursor, binned, off, srcs);

  // layer 1: one node per wave, 12500 blocks (R0-proven)
  k_agg<false><<<NODE_BLKS, 256, 0, stream>>>(xb, off, srcs, nullptr, nullptr,
                                              nullptr, nullptr, agg);
  k_gemm<true, false><<<GG, 256, 0, stream>>>(agg, xb, wl1b, wr1b, wresb, bl1, bres,
                                              buf0, resb, stats,
                                              nullptr, nullptr, nullptr, nullptr);

  // layer 2: persistent grid-stride, 2048 blocks (8/CU) — proven neutral
  k_agg<true><<<AGG_PERSIST, 256, 0, stream>>>(buf0, off, srcs, stats, g1w, g1b,
                                               g1a, agg);
  k_gemm<false, true><<<GG, 256, 0, stream>>>(agg, buf0, wl2b, wr2b, nullptr, bl2,
                                              nullptr, xb, nullptr, stats + 256,
                                              stats, g1w, g1b, g1a);
  k_norm2<<<1024, 256, 0, stream>>>(xb, stats + 256, g2w, g2b, g2a, resb, outp);
}